// Round 1
// baseline (49.738 us; speedup 1.0000x reference)
//
#include <hip/hip_runtime.h>
#include <math.h>

// Problem geometry (fixed by the reference).
constexpr int Bc = 32, Fc = 513, Tc = 1600;
constexpr int BLK = 128;                  // threads per block (2 waves)
constexpr int VEC = 4;                    // float4 per thread
constexpr int TT  = BLK * VEC;            // 512 t per block tile
constexpr int NTT = (Tc + TT - 1) / TT;   // 4 t-tiles (last partial: 64)
constexpr int FCH = 27;                   // f rows per block (513 = 19*27)
constexpr int NFC = (Fc + FCH - 1) / FCH; // 19 f-chunks
constexpr int NBLK = Bc * NFC * NTT;      // 2432 blocks
constexpr long long NTOT = (long long)Bc * Fc * Tc;  // 26,265,600

__device__ __forceinline__ float anti_wrap_f(float x) {
    // |x - round(x/2pi)*2pi|, round-half-even == jnp.round
    float r = rintf(x * 0.15915494309189535f);
    return fabsf(fmaf(-r, 6.283185307179586f, x));
}

// Reduce three per-thread floats across the block; result valid in thread 0.
__device__ __forceinline__ void block_reduce3(float& a, float& b, float& c) {
    #pragma unroll
    for (int off = 32; off > 0; off >>= 1) {
        a += __shfl_down(a, off);
        b += __shfl_down(b, off);
        c += __shfl_down(c, off);
    }
    __shared__ float sm[3][BLK / 64];
    const int lane = threadIdx.x & 63, wid = threadIdx.x >> 6;
    if (lane == 0) { sm[0][wid] = a; sm[1][wid] = b; sm[2][wid] = c; }
    __syncthreads();
    if (threadIdx.x == 0) {
        a = sm[0][0]; b = sm[1][0]; c = sm[2][0];
        #pragma unroll
        for (int w = 1; w < BLK / 64; ++w) {
            a += sm[0][w]; b += sm[1][w]; c += sm[2][w];
        }
    }
}

__global__ __launch_bounds__(BLK) void phase_main(
        const float* __restrict__ pr, const float* __restrict__ pg,
        float* __restrict__ partials,   // [3][NBLK] when two-stage
        float* __restrict__ out,        // atomic fallback target
        int use_atomic)
{
    const int tile = blockIdx.x;   // t tile
    const int fc   = blockIdx.y;   // f chunk
    const int b    = blockIdx.z;   // batch
    const int t0   = tile * TT + (int)threadIdx.x * VEC;
    const int f0   = fc * FCH;
    const int f1   = min(f0 + FCH, Fc);

    float s_ip = 0.f, s_gd = 0.f, s_ptd = 0.f;

    if (t0 < Tc) {  // Tc % VEC == 0, so a thread's 4 elems are all-valid or none
        const size_t baseb = (size_t)b * Fc * Tc + (size_t)t0;
        // Previous-row d (f-1 neighbor), carried in registers across the f loop.
        float4 pd;
        if (f0 == 0) {
            pd = make_float4(0.f, 0.f, 0.f, 0.f);  // implicit zero pad at f=-1
        } else {
            const float* ap = pr + baseb + (size_t)(f0 - 1) * Tc;
            const float* gp = pg + baseb + (size_t)(f0 - 1) * Tc;
            float4 a = *(const float4*)ap;
            float4 g = *(const float4*)gp;
            pd = make_float4(a.x - g.x, a.y - g.y, a.z - g.z, a.w - g.w);
        }
        for (int f = f0; f < f1; ++f) {
            const float* ap = pr + baseb + (size_t)f * Tc;
            const float* gp = pg + baseb + (size_t)f * Tc;
            float4 a = *(const float4*)ap;
            float4 g = *(const float4*)gp;
            float dm1 = 0.f;                     // d at t-1 (0 at global t==0)
            if (t0 > 0) dm1 = ap[-1] - gp[-1];   // same cache line / L1 hit
            float4 d = make_float4(a.x - g.x, a.y - g.y, a.z - g.z, a.w - g.w);

            s_ip  += anti_wrap_f(d.x) + anti_wrap_f(d.y)
                   + anti_wrap_f(d.z) + anti_wrap_f(d.w);
            s_gd  += anti_wrap_f(pd.x - d.x) + anti_wrap_f(pd.y - d.y)
                   + anti_wrap_f(pd.z - d.z) + anti_wrap_f(pd.w - d.w);
            s_ptd += anti_wrap_f(dm1 - d.x) + anti_wrap_f(d.x - d.y)
                   + anti_wrap_f(d.y - d.z) + anti_wrap_f(d.z - d.w);
            pd = d;
        }
    }

    block_reduce3(s_ip, s_gd, s_ptd);

    if (threadIdx.x == 0) {
        if (use_atomic) {
            const float invN = (float)(1.0 / (double)NTOT);
            atomicAdd(out + 0, s_ip * invN);
            atomicAdd(out + 1, s_gd * invN);
            atomicAdd(out + 2, s_ptd * invN);
        } else {
            const int bid = (blockIdx.z * gridDim.y + blockIdx.y) * gridDim.x
                          + blockIdx.x;
            partials[0 * NBLK + bid] = s_ip;
            partials[1 * NBLK + bid] = s_gd;
            partials[2 * NBLK + bid] = s_ptd;
        }
    }
}

__global__ __launch_bounds__(256) void phase_reduce(
        const float* __restrict__ partials, float* __restrict__ out)
{
    __shared__ float sm[4];
    const int tid = threadIdx.x;
    const int lane = tid & 63, wid = tid >> 6;
    for (int c = 0; c < 3; ++c) {
        float s = 0.f;
        for (int i = tid; i < NBLK; i += 256) s += partials[c * NBLK + i];
        #pragma unroll
        for (int off = 32; off > 0; off >>= 1) s += __shfl_down(s, off);
        __syncthreads();           // protect sm reuse across iterations
        if (lane == 0) sm[wid] = s;
        __syncthreads();
        if (tid == 0) {
            float t = sm[0] + sm[1] + sm[2] + sm[3];
            out[c] = t * (float)(1.0 / (double)NTOT);
        }
    }
}

__global__ void zero3(float* out) {
    if (threadIdx.x < 3) out[threadIdx.x] = 0.f;
}

extern "C" void kernel_launch(void* const* d_in, const int* in_sizes, int n_in,
                              void* d_out, int out_size, void* d_ws, size_t ws_size,
                              hipStream_t stream) {
    const float* pr = (const float*)d_in[0];
    const float* pg = (const float*)d_in[1];
    float* out = (float*)d_out;
    dim3 grid(NTT, NFC, Bc);

    if (ws_size >= (size_t)NBLK * 3 * sizeof(float)) {
        float* partials = (float*)d_ws;
        phase_main<<<grid, BLK, 0, stream>>>(pr, pg, partials, nullptr, 0);
        phase_reduce<<<1, 256, 0, stream>>>(partials, out);
    } else {
        zero3<<<1, 64, 0, stream>>>(out);
        phase_main<<<grid, BLK, 0, stream>>>(pr, pg, nullptr, out, 1);
    }
}